// Round 1
// baseline (303.942 us; speedup 1.0000x reference)
//
#include <hip/hip_runtime.h>
#include <math.h>

namespace {
constexpr int S = 64;
constexpr int NP = 131072;
constexpr int H = 32;
constexpr int BLK = 256;
constexpr int MAXC = 4096;           // max pts/cell (mean 2048, std ~45 -> safe)
constexpr int NCHUNK = MAXC / BLK;   // 16

// d_ws layout (as int array):
// [0,64)   hist   [64,128) off   [128,192) cursor
// [256, 256+NP) cell    [256+NP, 256+2*NP) list      (~1.05 MB total)
constexpr int WS_HIST = 0;
constexpr int WS_OFF  = 64;
constexpr int WS_CUR  = 128;
constexpr int WS_CELL = 256;
constexpr int WS_LIST = 256 + NP;

__device__ __forceinline__ float fast_tanh(float v) {
    float av = fabsf(v);
    float e  = __expf(-2.0f * av);
    float r  = __fdividef(1.0f - e, 1.0f + e);
    return copysignf(r, v);
}
__device__ __forceinline__ float fast_sigmoid(float z) {
    return __fdividef(1.0f, 1.0f + __expf(-z));   // z << 0: exp->inf -> 0, matches ref underflow
}

__global__ void k_init(int* hist) { hist[threadIdx.x] = 0; }

__global__ void k_hist(const float* __restrict__ x, int* __restrict__ hist,
                       int* __restrict__ cell) {
    __shared__ int lh[S];
    int tid = threadIdx.x;
    if (tid < S) lh[tid] = 0;
    __syncthreads();
    int p = blockIdx.x * blockDim.x + tid;
    if (p < NP) {
        float xx = x[2 * p + 1];
        int c = (int)floorf((xx + 1.0f) * 32.0f);
        c = min(S - 1, max(0, c));
        cell[p] = c;
        atomicAdd(&lh[c], 1);
    }
    __syncthreads();
    if (tid < S && lh[tid] != 0) atomicAdd(&hist[tid], lh[tid]);
}

__global__ void k_scan(const int* __restrict__ hist, int* __restrict__ off,
                       int* __restrict__ cursor) {
    int a = 0;
    for (int i = 0; i < S; ++i) { off[i] = a; cursor[i] = a; a += hist[i]; }
}

__global__ void k_scatter(const int* __restrict__ cell, int* __restrict__ cursor,
                          int* __restrict__ list) {
    int p = blockIdx.x * blockDim.x + threadIdx.x;
    if (p < NP) {
        int pos = atomicAdd(&cursor[cell[p]], 1);
        list[pos] = p;
    }
}

__global__ __launch_bounds__(BLK) void k_main(
    const float* __restrict__ x,
    const float* __restrict__ lo_core, const float* __restrict__ hi_core,
    const float* __restrict__ lo_ext,  const float* __restrict__ hi_ext,
    const float* __restrict__ W_in,  const float* __restrict__ b_in,
    const float* __restrict__ W_h1,  const float* __restrict__ b_h1,
    const float* __restrict__ W_h2,  const float* __restrict__ b_h2,
    const float* __restrict__ W_out, const float* __restrict__ b_out,
    const int* __restrict__ hist, const int* __restrict__ off,
    const int* __restrict__ list,
    float* __restrict__ out)
{
    const int c   = blockIdx.x;            // cell id (uniform)
    const int cnt = hist[c];
    const int base = blockIdx.y * BLK;
    if (base >= cnt) return;
    const int idx = base + (int)threadIdx.x;
    const bool active = idx < cnt;
    const int o = off[c];
    const int p = list[o + (active ? idx : 0)];
    const float tt = x[2 * p + 0];
    const float xx = x[2 * p + 1];

    float num = 0.0f, den = 0.0f;
    const int jlo = (c > 0) ? c - 1 : 0;
    const int jhi = (c < S - 1) ? c + 1 : S - 1;
    for (int j = jlo; j <= jhi; ++j) {     // uniform trip count (2 or 3)
        const float le0 = lo_ext[2*j+0], he0 = hi_ext[2*j+0];
        const float le1 = lo_ext[2*j+1], he1 = hi_ext[2*j+1];
        const float ctr0 = (le0 + he0) * 0.5f, hw0 = (he0 - le0) * 0.5f;
        const float ctr1 = (le1 + he1) * 0.5f, hw1 = (he1 - le1) * 0.5f;
        const float xn0 = (tt - ctr0) / hw0;
        const float xn1 = (xx - ctr1) / hw1;

        const float* Wi = W_in + j * (H * 2);
        const float* bi = b_in + j * H;
        float h0[H], h1v[H];
        #pragma unroll
        for (int k = 0; k < H; ++k) {
            float a = fmaf(xn1, Wi[2*k+1], fmaf(xn0, Wi[2*k], bi[k]));
            h0[k] = fast_tanh(a);
        }
        const float* W1 = W_h1 + j * (H * H);
        const float* b1 = b_h1 + j * H;
        #pragma unroll
        for (int k = 0; k < H; ++k) {
            float a = b1[k];
            #pragma unroll
            for (int q = 0; q < H; ++q) a = fmaf(h0[q], W1[k*H+q], a);
            h1v[k] = fast_tanh(a);
        }
        const float* W2 = W_h2 + j * (H * H);
        const float* b2 = b_h2 + j * H;
        #pragma unroll
        for (int k = 0; k < H; ++k) {
            float a = b2[k];
            #pragma unroll
            for (int q = 0; q < H; ++q) a = fmaf(h1v[q], W2[k*H+q], a);
            h0[k] = fast_tanh(a);
        }
        const float* Wo = W_out + j * H;
        float acc = b_out[j];
        #pragma unroll
        for (int q = 0; q < H; ++q) acc = fmaf(h0[q], Wo[q], acc);
        // acc * SCALE + SHIFT with SCALE=1, SHIFT=0 -> acc

        // sigmoid-product window, both dims (computed exactly as reference)
        float w = 1.0f;
        {
            const float lc = lo_core[2*j+0], hc = hi_core[2*j+0];
            const float ov = fmaxf(he0 - hc, lc - le0);
            const float wd = he0 - le0;
            const float sc = __fdividef(4.0f, fmaf(2.0f * ov, wd, 1e-8f));
            w *= fast_sigmoid(sc * (tt - lc)) * fast_sigmoid(sc * (hc - tt));
        }
        {
            const float lc = lo_core[2*j+1], hc = hi_core[2*j+1];
            const float ov = fmaxf(he1 - hc, lc - le1);
            const float wd = he1 - le1;
            const float sc = __fdividef(4.0f, fmaf(2.0f * ov, wd, 1e-8f));
            w *= fast_sigmoid(sc * (xx - lc)) * fast_sigmoid(sc * (hc - xx));
        }
        num = fmaf(acc, w, num);
        den += w;
    }
    const float u = num / (den + 1e-8f);
    const float g = -sinf(3.14159265358979323846f * xx);
    const float factor = fast_tanh(xx + 1.0f) * fast_tanh(xx - 1.0f) * fast_tanh(tt);
    if (active) out[p] = fmaf(factor, u, g);
}
} // namespace

extern "C" void kernel_launch(void* const* d_in, const int* in_sizes, int n_in,
                              void* d_out, int out_size, void* d_ws, size_t ws_size,
                              hipStream_t stream) {
    const float* x       = (const float*)d_in[0];
    const float* lo_core = (const float*)d_in[1];
    const float* hi_core = (const float*)d_in[2];
    const float* lo_ext  = (const float*)d_in[3];
    const float* hi_ext  = (const float*)d_in[4];
    const float* W_in    = (const float*)d_in[5];
    const float* b_in    = (const float*)d_in[6];
    const float* W_h1    = (const float*)d_in[7];
    const float* b_h1    = (const float*)d_in[8];
    const float* W_h2    = (const float*)d_in[9];
    const float* b_h2    = (const float*)d_in[10];
    const float* W_out   = (const float*)d_in[11];
    const float* b_out   = (const float*)d_in[12];
    float* out = (float*)d_out;

    int* ws     = (int*)d_ws;
    int* hist   = ws + WS_HIST;
    int* off    = ws + WS_OFF;
    int* cursor = ws + WS_CUR;
    int* cell   = ws + WS_CELL;
    int* list   = ws + WS_LIST;

    hipLaunchKernelGGL(k_init,    dim3(1),        dim3(S),   0, stream, hist);
    hipLaunchKernelGGL(k_hist,    dim3(NP/BLK),   dim3(BLK), 0, stream, x, hist, cell);
    hipLaunchKernelGGL(k_scan,    dim3(1),        dim3(1),   0, stream, hist, off, cursor);
    hipLaunchKernelGGL(k_scatter, dim3(NP/BLK),   dim3(BLK), 0, stream, cell, cursor, list);
    hipLaunchKernelGGL(k_main,    dim3(S, NCHUNK), dim3(BLK), 0, stream,
        x, lo_core, hi_core, lo_ext, hi_ext, W_in, b_in, W_h1, b_h1,
        W_h2, b_h2, W_out, b_out, hist, off, list, out);
}

// Round 2
// 112.646 us; speedup vs baseline: 2.6982x; 2.6982x over previous
//
#include <hip/hip_runtime.h>
#include <math.h>

namespace {
constexpr int S = 64;
constexpr int NP = 131072;
constexpr int H = 32;
constexpr int BLK = 256;
constexpr int NB = NP / BLK;         // 512 blocks in hist/scatter
constexpr int MAXC = 4096;           // max pts/cell (mean 2048, std ~45 -> safe)
constexpr int NCHUNK = MAXC / BLK;   // 16

// d_ws layout (as int array):
// [0,64)  hist(total per cell)   [64,128) off
// [128, 128+NB*S)        blockhist -> (in-place) per-(block,cell) base
// [128+NB*S, +NP)        cell
// [..., +NP)             list                      (~1.18 MB total)
constexpr int WS_HIST = 0;
constexpr int WS_OFF  = 64;
constexpr int WS_BH   = 128;
constexpr int WS_CELL = WS_BH + NB * S;
constexpr int WS_LIST = WS_CELL + NP;

__device__ __forceinline__ float fast_tanh(float v) {
    float av = fabsf(v);
    float e  = __expf(-2.0f * av);
    float r  = __fdividef(1.0f - e, 1.0f + e);
    return copysignf(r, v);
}
__device__ __forceinline__ float fast_sigmoid(float z) {
    return __fdividef(1.0f, 1.0f + __expf(-z));   // z << 0: exp->inf -> 0, matches ref underflow
}

__device__ __forceinline__ int cell_of(float xx) {
    int c = (int)floorf((xx + 1.0f) * 32.0f);
    return min(S - 1, max(0, c));
}

// per-block histogram, no global atomics
__global__ __launch_bounds__(BLK) void k_hist(const float* __restrict__ x,
                                              int* __restrict__ blockhist,
                                              int* __restrict__ cell) {
    __shared__ int lh[S];
    const int tid = threadIdx.x;
    if (tid < S) lh[tid] = 0;
    __syncthreads();
    const int p = blockIdx.x * BLK + tid;          // NP % BLK == 0
    const int c = cell_of(x[2 * p + 1]);
    cell[p] = c;
    atomicAdd(&lh[c], 1);                          // LDS atomic only
    __syncthreads();
    if (tid < S) blockhist[blockIdx.x * S + tid] = lh[tid];
}

// one block of 64 threads; thread c owns cell c.
__global__ __launch_bounds__(S) void k_scan(int* __restrict__ blockhist,
                                            int* __restrict__ hist,
                                            int* __restrict__ off) {
    const int c = threadIdx.x;
    int tot = 0;
    for (int b = 0; b < NB; ++b) tot += blockhist[b * S + c];   // coalesced
    __shared__ int totals[S];
    totals[c] = tot;
    __syncthreads();
    int o = 0;
    for (int i = 0; i < c; ++i) o += totals[i];
    hist[c] = tot;
    off[c]  = o;
    int running = o;
    for (int b = 0; b < NB; ++b) {                  // blockhist -> base, in place
        int v = blockhist[b * S + c];
        blockhist[b * S + c] = running;
        running += v;
    }
}

// scatter with LDS-rank + precomputed per-(block,cell) base; no global atomics
__global__ __launch_bounds__(BLK) void k_scatter(const float* __restrict__ x,
                                                 const int* __restrict__ cell,
                                                 const int* __restrict__ base,
                                                 int* __restrict__ list) {
    __shared__ int lh[S];
    __shared__ int lbase[S];
    const int tid = threadIdx.x;
    if (tid < S) { lh[tid] = 0; lbase[tid] = base[blockIdx.x * S + tid]; }
    __syncthreads();
    const int p = blockIdx.x * BLK + tid;
    const int c = cell[p];
    const int r = atomicAdd(&lh[c], 1);             // LDS atomic only
    list[lbase[c] + r] = p;
}

__global__ __launch_bounds__(BLK) void k_main(
    const float* __restrict__ x,
    const float* __restrict__ lo_core, const float* __restrict__ hi_core,
    const float* __restrict__ lo_ext,  const float* __restrict__ hi_ext,
    const float* __restrict__ W_in,  const float* __restrict__ b_in,
    const float* __restrict__ W_h1,  const float* __restrict__ b_h1,
    const float* __restrict__ W_h2,  const float* __restrict__ b_h2,
    const float* __restrict__ W_out, const float* __restrict__ b_out,
    const int* __restrict__ hist, const int* __restrict__ off,
    const int* __restrict__ list,
    float* __restrict__ out)
{
    const int c   = blockIdx.x;            // cell id (uniform)
    const int cnt = hist[c];
    const int base = blockIdx.y * BLK;
    if (base >= cnt) return;
    const int idx = base + (int)threadIdx.x;
    const bool active = idx < cnt;
    const int o = off[c];
    const int p = list[o + (active ? idx : 0)];
    const float tt = x[2 * p + 0];
    const float xx = x[2 * p + 1];

    float num = 0.0f, den = 0.0f;
    const int jlo = (c > 0) ? c - 1 : 0;
    const int jhi = (c < S - 1) ? c + 1 : S - 1;
    for (int j = jlo; j <= jhi; ++j) {     // uniform trip count (2 or 3)
        const float le0 = lo_ext[2*j+0], he0 = hi_ext[2*j+0];
        const float le1 = lo_ext[2*j+1], he1 = hi_ext[2*j+1];
        const float ctr0 = (le0 + he0) * 0.5f, hw0 = (he0 - le0) * 0.5f;
        const float ctr1 = (le1 + he1) * 0.5f, hw1 = (he1 - le1) * 0.5f;
        const float xn0 = (tt - ctr0) / hw0;
        const float xn1 = (xx - ctr1) / hw1;

        const float* Wi = W_in + j * (H * 2);
        const float* bi = b_in + j * H;
        float h0[H], h1v[H];
        #pragma unroll
        for (int k = 0; k < H; ++k) {
            float a = fmaf(xn1, Wi[2*k+1], fmaf(xn0, Wi[2*k], bi[k]));
            h0[k] = fast_tanh(a);
        }
        const float* W1 = W_h1 + j * (H * H);
        const float* b1 = b_h1 + j * H;
        #pragma unroll
        for (int k = 0; k < H; ++k) {
            float a = b1[k];
            #pragma unroll
            for (int q = 0; q < H; ++q) a = fmaf(h0[q], W1[k*H+q], a);
            h1v[k] = fast_tanh(a);
        }
        const float* W2 = W_h2 + j * (H * H);
        const float* b2 = b_h2 + j * H;
        #pragma unroll
        for (int k = 0; k < H; ++k) {
            float a = b2[k];
            #pragma unroll
            for (int q = 0; q < H; ++q) a = fmaf(h1v[q], W2[k*H+q], a);
            h0[k] = fast_tanh(a);
        }
        const float* Wo = W_out + j * H;
        float acc = b_out[j];
        #pragma unroll
        for (int q = 0; q < H; ++q) acc = fmaf(h0[q], Wo[q], acc);
        // acc * SCALE + SHIFT with SCALE=1, SHIFT=0 -> acc

        // sigmoid-product window, both dims (computed exactly as reference)
        float w = 1.0f;
        {
            const float lc = lo_core[2*j+0], hc = hi_core[2*j+0];
            const float ov = fmaxf(he0 - hc, lc - le0);
            const float wd = he0 - le0;
            const float sc = __fdividef(4.0f, fmaf(2.0f * ov, wd, 1e-8f));
            w *= fast_sigmoid(sc * (tt - lc)) * fast_sigmoid(sc * (hc - tt));
        }
        {
            const float lc = lo_core[2*j+1], hc = hi_core[2*j+1];
            const float ov = fmaxf(he1 - hc, lc - le1);
            const float wd = he1 - le1;
            const float sc = __fdividef(4.0f, fmaf(2.0f * ov, wd, 1e-8f));
            w *= fast_sigmoid(sc * (xx - lc)) * fast_sigmoid(sc * (hc - xx));
        }
        num = fmaf(acc, w, num);
        den += w;
    }
    const float u = num / (den + 1e-8f);
    const float g = -sinf(3.14159265358979323846f * xx);
    const float factor = fast_tanh(xx + 1.0f) * fast_tanh(xx - 1.0f) * fast_tanh(tt);
    if (active) out[p] = fmaf(factor, u, g);
}
} // namespace

extern "C" void kernel_launch(void* const* d_in, const int* in_sizes, int n_in,
                              void* d_out, int out_size, void* d_ws, size_t ws_size,
                              hipStream_t stream) {
    const float* x       = (const float*)d_in[0];
    const float* lo_core = (const float*)d_in[1];
    const float* hi_core = (const float*)d_in[2];
    const float* lo_ext  = (const float*)d_in[3];
    const float* hi_ext  = (const float*)d_in[4];
    const float* W_in    = (const float*)d_in[5];
    const float* b_in    = (const float*)d_in[6];
    const float* W_h1    = (const float*)d_in[7];
    const float* b_h1    = (const float*)d_in[8];
    const float* W_h2    = (const float*)d_in[9];
    const float* b_h2    = (const float*)d_in[10];
    const float* W_out   = (const float*)d_in[11];
    const float* b_out   = (const float*)d_in[12];
    float* out = (float*)d_out;

    int* ws        = (int*)d_ws;
    int* hist      = ws + WS_HIST;
    int* off       = ws + WS_OFF;
    int* blockhist = ws + WS_BH;    // becomes per-(block,cell) base after k_scan
    int* cell      = ws + WS_CELL;
    int* list      = ws + WS_LIST;

    hipLaunchKernelGGL(k_hist,    dim3(NB),        dim3(BLK), 0, stream, x, blockhist, cell);
    hipLaunchKernelGGL(k_scan,    dim3(1),         dim3(S),   0, stream, blockhist, hist, off);
    hipLaunchKernelGGL(k_scatter, dim3(NB),        dim3(BLK), 0, stream, x, cell, blockhist, list);
    hipLaunchKernelGGL(k_main,    dim3(S, NCHUNK), dim3(BLK), 0, stream,
        x, lo_core, hi_core, lo_ext, hi_ext, W_in, b_in, W_h1, b_h1,
        W_h2, b_h2, W_out, b_out, hist, off, list, out);
}

// Round 4
// 87.401 us; speedup vs baseline: 3.4776x; 1.2888x over previous
//
#include <hip/hip_runtime.h>
#include <math.h>

namespace {
constexpr int S = 64;
constexpr int NP = 131072;
constexpr int H = 32;
constexpr int BLK = 256;
constexpr int NB = NP / BLK;       // 512
constexpr int CH = 64;             // points per k_main chunk (one lane each)
constexpr int NCHUNK = 40;         // 40*64 = 2560 >= max cell count (~2160, +11 sigma)

// d_ws layout (ints):
constexpr int WS_HIST = 0;                  // [0,64)
constexpr int WS_OFF  = 64;                 // [64,128)
constexpr int WS_CUR  = 128;                // [128,192)
constexpr int WS_CELL = 192;                // [192, 192+NP)
constexpr int WS_LIST = WS_CELL + NP;       // [+NP)
constexpr int WS_XS   = WS_LIST + NP;       // float2[NP] -> 2*NP ints

__device__ __forceinline__ float dev_exp2(float v) {
    return __builtin_amdgcn_exp2f(v);       // v_exp_f32: 2^v, saturates to inf/0
}
__device__ __forceinline__ float fast_tanh(float v) {
    // tanh(v) = 1 - 2/(e^{2v}+1); exp2 overflow/underflow gives exact +-1 saturation
    float e = dev_exp2(v * 2.8853900817779268f);     // e^{2v}
    return 1.0f - __fdividef(2.0f, e + 1.0f);
}
__device__ __forceinline__ float fast_sigmoid(float z) {
    // z << 0: exp2(+big) -> inf -> 0, matching reference fp32 underflow
    return __fdividef(1.0f, 1.0f + dev_exp2(z * -1.4426950408889634f));
}
__device__ __forceinline__ int cell_of(float xx) {
    int c = (int)floorf((xx + 1.0f) * 32.0f);
    return min(S - 1, max(0, c));
}

__global__ void k_zero(int* hist) { hist[threadIdx.x] = 0; }

__global__ __launch_bounds__(BLK) void k_hist(const float* __restrict__ x,
                                              int* __restrict__ hist,
                                              int* __restrict__ cell) {
    __shared__ int lh[S];
    const int tid = threadIdx.x;
    if (tid < S) lh[tid] = 0;
    __syncthreads();
    const int p = blockIdx.x * BLK + tid;
    const int c = cell_of(x[2 * p + 1]);
    cell[p] = c;
    atomicAdd(&lh[c], 1);
    __syncthreads();
    if (tid < S && lh[tid] != 0) atomicAdd(&hist[tid], lh[tid]);   // 64 addrs, ~32K total
}

// one wave of 64: exclusive scan of hist -> off, cursor
__global__ __launch_bounds__(S) void k_off(const int* __restrict__ hist,
                                           int* __restrict__ off,
                                           int* __restrict__ cursor) {
    const int t = threadIdx.x;
    int v = hist[t];
    int sum = v;
    #pragma unroll
    for (int d = 1; d < 64; d <<= 1) {
        int o = __shfl_up(sum, d);
        if (t >= d) sum += o;
    }
    off[t] = sum - v;
    cursor[t] = sum - v;
}

// scatter: LDS rank + one global atomic per (block,cell); also pre-gather x into sorted order
__global__ __launch_bounds__(BLK) void k_scatter(const float* __restrict__ x,
                                                 const int* __restrict__ cell,
                                                 int* __restrict__ cursor,
                                                 int* __restrict__ list,
                                                 float2* __restrict__ xsorted) {
    __shared__ int lh[S];
    __shared__ int lbase[S];
    const int tid = threadIdx.x;
    if (tid < S) lh[tid] = 0;
    __syncthreads();
    const int p = blockIdx.x * BLK + tid;
    const int c = cell[p];
    const int r = atomicAdd(&lh[c], 1);            // LDS atomic: local rank
    __syncthreads();
    if (tid < S && lh[tid] != 0) lbase[tid] = atomicAdd(&cursor[tid], lh[tid]);
    __syncthreads();
    const int pos = lbase[c] + r;
    list[pos] = p;
    const float2 xv = ((const float2*)x)[p];
    xsorted[pos] = xv;
}

// block = 192 threads = 3 waves; wave w evaluates subnet j=c-1+w for 64 points
__global__ __launch_bounds__(192) void k_main(
    const float2* __restrict__ xsorted,
    const float* __restrict__ lo_core, const float* __restrict__ hi_core,
    const float* __restrict__ lo_ext,  const float* __restrict__ hi_ext,
    const float* __restrict__ W_in,  const float* __restrict__ b_in,
    const float* __restrict__ W_h1,  const float* __restrict__ b_h1,
    const float* __restrict__ W_h2,  const float* __restrict__ b_h2,
    const float* __restrict__ W_out, const float* __restrict__ b_out,
    const int* __restrict__ hist, const int* __restrict__ off,
    const int* __restrict__ list,
    float* __restrict__ out)
{
    const int c   = blockIdx.x;                  // cell id (uniform)
    const int cnt = hist[c];
    const int base = blockIdx.y * CH;
    if (base >= cnt) return;

    const int wid  = threadIdx.x >> 6;           // 0..2
    const int lane = threadIdx.x & 63;
    const int idx  = base + lane;
    const bool active = idx < cnt;
    const int slot = off[c] + (active ? idx : cnt - 1);
    const float2 xv = xsorted[slot];
    const float tt = xv.x, xx = xv.y;

    __shared__ float lnum[3][CH];
    __shared__ float lden[3][CH];

    float num = 0.0f, den = 0.0f;
    const int j = c - 1 + wid;
    if (j >= 0 && j < S) {                        // wave-uniform
        const int ju = __builtin_amdgcn_readfirstlane(j);
        const float le0 = lo_ext[2*ju+0], he0 = hi_ext[2*ju+0];
        const float le1 = lo_ext[2*ju+1], he1 = hi_ext[2*ju+1];
        const float xn0 = (tt - (le0 + he0) * 0.5f) / ((he0 - le0) * 0.5f);
        const float xn1 = (xx - (le1 + he1) * 0.5f) / ((he1 - le1) * 0.5f);

        const float* Wi = W_in + ju * (H * 2);
        const float* bi = b_in + ju * H;
        float h0[H], h1[H];
        #pragma unroll
        for (int k = 0; k < H; ++k) {
            float a = fmaf(xn1, Wi[2*k+1], fmaf(xn0, Wi[2*k], bi[k]));
            h0[k] = fast_tanh(a);
        }
        const float* W1 = W_h1 + ju * (H * H);
        const float* b1 = b_h1 + ju * H;
        #pragma unroll
        for (int k = 0; k < H; ++k) {
            float a = b1[k];
            #pragma unroll
            for (int q = 0; q < H; ++q) a = fmaf(h0[q], W1[k*H+q], a);
            h1[k] = fast_tanh(a);
        }
        const float* W2 = W_h2 + ju * (H * H);
        const float* b2 = b_h2 + ju * H;
        #pragma unroll
        for (int k = 0; k < H; ++k) {
            float a = b2[k];
            #pragma unroll
            for (int q = 0; q < H; ++q) a = fmaf(h1[q], W2[k*H+q], a);
            h0[k] = fast_tanh(a);                 // reuse h0 as layer-3 out
        }
        const float* Wo = W_out + ju * H;
        float acc = b_out[ju];
        #pragma unroll
        for (int q = 0; q < H; ++q) acc = fmaf(h0[q], Wo[q], acc);

        float w = 1.0f;
        {
            const float lc = lo_core[2*ju+0], hc = hi_core[2*ju+0];
            const float ov = fmaxf(he0 - hc, lc - le0);
            const float sc = __fdividef(4.0f, fmaf(2.0f * ov, he0 - le0, 1e-8f));
            w *= fast_sigmoid(sc * (tt - lc)) * fast_sigmoid(sc * (hc - tt));
        }
        {
            const float lc = lo_core[2*ju+1], hc = hi_core[2*ju+1];
            const float ov = fmaxf(he1 - hc, lc - le1);
            const float sc = __fdividef(4.0f, fmaf(2.0f * ov, he1 - le1, 1e-8f));
            w *= fast_sigmoid(sc * (xx - lc)) * fast_sigmoid(sc * (hc - xx));
        }
        num = acc * w;
        den = w;
    }
    lnum[wid][lane] = num;
    lden[wid][lane] = den;
    __syncthreads();

    if (threadIdx.x < CH && active) {             // wave 0 finishes its own 64 points
        const float nsum = lnum[0][lane] + lnum[1][lane] + lnum[2][lane];
        const float dsum = lden[0][lane] + lden[1][lane] + lden[2][lane];
        const float u = __fdividef(nsum, dsum + 1e-8f);
        const float g = -sinf(3.14159265358979323846f * xx);
        const float factor = fast_tanh(xx + 1.0f) * fast_tanh(xx - 1.0f) * fast_tanh(tt);
        const int p = list[slot];
        out[p] = fmaf(factor, u, g);
    }
}
} // namespace

extern "C" void kernel_launch(void* const* d_in, const int* in_sizes, int n_in,
                              void* d_out, int out_size, void* d_ws, size_t ws_size,
                              hipStream_t stream) {
    const float* x       = (const float*)d_in[0];
    const float* lo_core = (const float*)d_in[1];
    const float* hi_core = (const float*)d_in[2];
    const float* lo_ext  = (const float*)d_in[3];
    const float* hi_ext  = (const float*)d_in[4];
    const float* W_in    = (const float*)d_in[5];
    const float* b_in    = (const float*)d_in[6];
    const float* W_h1    = (const float*)d_in[7];
    const float* b_h1    = (const float*)d_in[8];
    const float* W_h2    = (const float*)d_in[9];
    const float* b_h2    = (const float*)d_in[10];
    const float* W_out   = (const float*)d_in[11];
    const float* b_out   = (const float*)d_in[12];
    float* out = (float*)d_out;

    int* ws      = (int*)d_ws;
    int* hist    = ws + WS_HIST;
    int* off     = ws + WS_OFF;
    int* cursor  = ws + WS_CUR;
    int* cell    = ws + WS_CELL;
    int* list    = ws + WS_LIST;
    float2* xsorted = (float2*)(ws + WS_XS);

    hipLaunchKernelGGL(k_zero,    dim3(1),          dim3(S),   0, stream, hist);
    hipLaunchKernelGGL(k_hist,    dim3(NB),         dim3(BLK), 0, stream, x, hist, cell);
    hipLaunchKernelGGL(k_off,     dim3(1),          dim3(S),   0, stream, hist, off, cursor);
    hipLaunchKernelGGL(k_scatter, dim3(NB),         dim3(BLK), 0, stream, x, cell, cursor, list, xsorted);
    hipLaunchKernelGGL(k_main,    dim3(S, NCHUNK),  dim3(192), 0, stream,
        xsorted, lo_core, hi_core, lo_ext, hi_ext, W_in, b_in, W_h1, b_h1,
        W_h2, b_h2, W_out, b_out, hist, off, list, out);
}